// Round 9
// baseline (3712.963 us; speedup 1.0000x reference)
//
#include <hip/hip_runtime.h>

#define HID 1024
#define G4 4096
#define TCH 128
#define NCH 4
#define NWG 256

typedef short short8 __attribute__((ext_vector_type(8)));
typedef float f32x4 __attribute__((ext_vector_type(4)));
typedef unsigned int u32x4 __attribute__((ext_vector_type(4)));

static __device__ __forceinline__ unsigned short f2bf(float f) {
    unsigned int u = __builtin_bit_cast(unsigned int, f);
    u += 0x7fffu + ((u >> 16) & 1u);
    return (unsigned short)(u >> 16);
}
static __device__ __forceinline__ unsigned short f2h(float v) {
    _Float16 h = (_Float16)v;
    return __builtin_bit_cast(unsigned short, h);
}
static __device__ __forceinline__ float h2f(unsigned short u) {
    return (float)__builtin_bit_cast(_Float16, u);
}

// fp32 -> bf16 bulk convert (n8 groups of 8)
__global__ void cvt_mat(const float* __restrict__ src, unsigned short* __restrict__ dst, int n8) {
    int idx = blockIdx.x * blockDim.x + threadIdx.x;
    if (idx >= n8) return;
    const float* s = src + (size_t)idx * 8;
    float4 a = *(const float4*)s;
    float4 b = *(const float4*)(s + 4);
    short8 v;
    v[0]=(short)f2bf(a.x); v[1]=(short)f2bf(a.y); v[2]=(short)f2bf(a.z); v[3]=(short)f2bf(a.w);
    v[4]=(short)f2bf(b.x); v[5]=(short)f2bf(b.y); v[6]=(short)f2bf(b.z); v[7]=(short)f2bf(b.w);
    *(short8*)(dst + (size_t)idx * 8) = v;
}

// zero state region (hcan, cws, hx, flags), combine biases
__global__ void init_kernel(const float* __restrict__ bih, const float* __restrict__ bhh,
                            float* __restrict__ biasc, unsigned int* __restrict__ zbase, int nz) {
    int i = blockIdx.x * blockDim.x + threadIdx.x;
    if (i < nz) zbase[i] = 0u;
    if (i < G4) biasc[i] = bih[i] + bhh[i];
}

// xg[m][g] = sum_k x_chunk[m][k]*Wih[g][k], m = tl*64 + n; output f16 bits.
__global__ __launch_bounds__(256) void xg_gemm(
    const float* __restrict__ x,            // [64][512][1024] fp32
    const unsigned short* __restrict__ wb,  // Wih_bf [4096][1024]
    unsigned short* __restrict__ xg,        // [TCH*64][4096] f16 chunk
    int t0) {
    __shared__ unsigned short Al[128][72];
    __shared__ unsigned short Bl[128][72];
    const int tid = threadIdx.x, w = tid >> 6, lane = tid & 63;
    const int bm = blockIdx.x >> 5, bn = blockIdx.x & 31;
    const int wr = w >> 1, wc = w & 1;
    const int fr = lane & 15, kg = lane >> 4;
    f32x4 acc[4][4];
    #pragma unroll
    for (int i = 0; i < 4; ++i)
        #pragma unroll
        for (int j = 0; j < 4; ++j) acc[i][j] = (f32x4){0.f,0.f,0.f,0.f};

    for (int kt = 0; kt < 16; ++kt) {
        __syncthreads();
        #pragma unroll
        for (int c = 0; c < 4; ++c) {
            int idx = c * 256 + tid;
            int row = idx >> 3, co = (idx & 7) * 8;
            int m = bm * 128 + row;
            const float* sp = x + ((size_t)(m & 63) * 512 + (size_t)(t0 + (m >> 6))) * 1024
                                + kt * 64 + co;
            float4 a = *(const float4*)sp;
            float4 b = *(const float4*)(sp + 4);
            short8 v;
            v[0]=(short)f2bf(a.x); v[1]=(short)f2bf(a.y); v[2]=(short)f2bf(a.z); v[3]=(short)f2bf(a.w);
            v[4]=(short)f2bf(b.x); v[5]=(short)f2bf(b.y); v[6]=(short)f2bf(b.z); v[7]=(short)f2bf(b.w);
            *(short8*)&Al[row][co] = v;
            *(short8*)&Bl[row][co] = *(const short8*)(wb + (size_t)(bn * 128 + row) * 1024 + kt * 64 + co);
        }
        __syncthreads();
        #pragma unroll
        for (int kb = 0; kb < 2; ++kb) {
            short8 af[4], bf_[4];
            #pragma unroll
            for (int mi = 0; mi < 4; ++mi)
                af[mi] = *(const short8*)&Al[wr*64 + mi*16 + fr][kb*32 + kg*8];
            #pragma unroll
            for (int ni = 0; ni < 4; ++ni)
                bf_[ni] = *(const short8*)&Bl[wc*64 + ni*16 + fr][kb*32 + kg*8];
            #pragma unroll
            for (int mi = 0; mi < 4; ++mi)
                #pragma unroll
                for (int ni = 0; ni < 4; ++ni)
                    acc[mi][ni] = __builtin_amdgcn_mfma_f32_16x16x32_bf16(af[mi], bf_[ni], acc[mi][ni], 0, 0, 0);
        }
    }
    #pragma unroll
    for (int mi = 0; mi < 4; ++mi)
        #pragma unroll
        for (int ni = 0; ni < 4; ++ni)
            #pragma unroll
            for (int r = 0; r < 4; ++r) {
                int row = bm*128 + wr*64 + mi*16 + kg*4 + r;
                int col = bn*128 + wc*64 + ni*16 + fr;
                xg[(size_t)row * 4096 + col] = f2h(acc[mi][ni][r]);
            }
}

// Persistent LSTM chunk (128 steps). 256 WGs x 512 thr.
// 8 INDEPENDENT groups: G = blockIdx>>5 owns batch rows [G*8,+8); member l = blockIdx&31
// owns hidden units [l*32,+32). Whh slice in 128 VGPRs/thread. No cross-group sync.
// Transport (all sc0 sc1 = device scope, R4/5/8-proven):
//   producer: bf16 short stores (fire+forget) -> per-wave vmcnt(0) drain -> lane0
//             stores ONE flag dword = t+1 (release). 4 flags per WG (one per
//             pointwise wave) -> no extra __syncthreads.
//   consumer: all waves poll the group's 128-dword flag block (dwordx4 per lane<32,
//             128 B/WG/iter -- 256x less poll traffic than R8) then load the 16 KB
//             h data exactly once.
__global__ __launch_bounds__(512, 2) void lstm_persist(
    const unsigned short* __restrict__ whh,   // Whh_bf [4096][1024]
    const unsigned short* __restrict__ xg,    // [TCH*64][4096] f16 bits
    const float* __restrict__ biasc,          // [4096]
    unsigned short* __restrict__ hcan,        // [64][1024] bf16 chunk-boundary h
    unsigned short* __restrict__ hx,          // [2][8][8][1024] bf16 h exchange
    float* __restrict__ cws,                  // [64][1024] chunk-boundary c
    unsigned int* __restrict__ flags,         // [8][32][4]
    float* __restrict__ y, int t0) {
    __shared__ unsigned short hA[16 * 1024];   // [16][1024] bf16, rows 8..15 zero, swizzled
    __shared__ float sgate[4][2][8][16];
    __shared__ float sbias[4][32];

    const int tid = threadIdx.x, w = tid >> 6, lane = tid & 63;
    const int G = (int)(blockIdx.x >> 5);
    const int l = (int)(blockIdx.x & 31);

    for (int i = tid; i < 8192; i += 512) hA[8192 + i] = 0;   // zero pad rows 8..15
    if (tid < 128) {
        int q = tid >> 5, j = tid & 31;
        sbias[q][j] = biasc[q * 1024 + l * 32 + j];
    }
    const int q = w & 3, hu = w >> 2;
    const int col = lane & 15, kg = lane >> 4;

    short8 bfr[32];   // Whh rows q*1024 + l*32 + hu*16 + col, K=1024
    {
        const unsigned short* wp = whh + (size_t)(q * 1024 + l * 32 + hu * 16 + col) * 1024 + kg * 8;
        #pragma unroll
        for (int kb = 0; kb < 32; ++kb) bfr[kb] = *(const short8*)(wp + kb * 32);
    }
    float creg = 0.f;
    if (tid < 256) {
        int n = tid >> 5, j = tid & 31;
        creg = cws[((size_t)(G * 8 + n) << 10) + l * 32 + j];
    }
    __syncthreads();

    const int sn = tid >> 6;   // staging batch row 0..7 (one per wave)
    unsigned short* hxb0 = hx + (size_t)G * 8192;
    unsigned short* hxb1 = hx + (size_t)(8 + G) * 8192;
    const unsigned int* fgrp = flags + G * 128 + (lane & 31) * 4;

    for (int s = 0; s < TCH; ++s) {
        const int t = t0 + s;
        // ---- xg prefetch (plain loads; complete under the poll) ----
        unsigned short xi = 0, xf = 0, xgv = 0, xo = 0;
        if (tid < 256) {
            int n = tid >> 5, j = tid & 31;
            const unsigned short* xp = xg + ((size_t)(s * 64 + G * 8 + n) << 12) + l * 32 + j;
            xi = xp[0]; xf = xp[1024]; xgv = xp[2048]; xo = xp[3072];
        }
        // ---- acquire h(t) ----
        short8 v0, v1;
        if (s == 0) {
            const unsigned short* hp = hcan + ((size_t)(G * 8 + sn) << 10) + lane * 16;
            v0 = *(const short8*)hp;
            v1 = *(const short8*)(hp + 8);
        } else {
            const unsigned int tgt = (unsigned int)t;
            int guard = 0;
            while (true) {
                u32x4 fv = {tgt, tgt, tgt, tgt};
                if (lane < 32)
                    asm volatile("global_load_dwordx4 %0, %1, off sc0 sc1\n\ts_waitcnt vmcnt(0)"
                                 : "=v"(fv) : "v"(fgrp) : "memory");
                int ok = (fv[0] >= tgt) & (fv[1] >= tgt) & (fv[2] >= tgt) & (fv[3] >= tgt);
                if (__all(ok) || ++guard > 100000) break;
            }
            const unsigned short* hp = ((t & 1) ? hxb1 : hxb0) + sn * 1024 + lane * 16;
            asm volatile("global_load_dwordx4 %0, %1, off sc0 sc1" : "=v"(v0) : "v"(hp) : "memory");
            asm volatile("global_load_dwordx4 %0, %1, off sc0 sc1" : "=v"(v1) : "v"(hp + 8) : "memory");
            asm volatile("s_waitcnt vmcnt(0)" ::: "memory");
            __builtin_amdgcn_sched_barrier(0);
        }
        {   // stage into hA (XOR-swizzled 16B groups)
            int cg0 = lane * 2;
            char* base = (char*)hA + sn * 2048;
            *(short8*)(base + (((unsigned)(cg0       ^ (sn & 7))) << 4)) = v0;
            *(short8*)(base + (((unsigned)((cg0 + 1) ^ (sn & 7))) << 4)) = v1;
        }
        __syncthreads();
        // ---- recurrent MFMA: M=16 (8 real rows) x N=16 units x K=1024 ----
        f32x4 acc0 = {0.f,0.f,0.f,0.f}, acc1 = {0.f,0.f,0.f,0.f};
        {
            const int row = lane & 15;
            const char* base = (const char*)hA + row * 2048;
            #pragma unroll
            for (int kb = 0; kb < 32; kb += 2) {
                int cgA = kb * 4 + kg;
                short8 a0 = *(const short8*)(base + (((unsigned)(cgA       ^ (row & 7))) << 4));
                short8 a1 = *(const short8*)(base + (((unsigned)((cgA + 4) ^ (row & 7))) << 4));
                acc0 = __builtin_amdgcn_mfma_f32_16x16x32_bf16(a0, bfr[kb],     acc0, 0, 0, 0);
                acc1 = __builtin_amdgcn_mfma_f32_16x16x32_bf16(a1, bfr[kb + 1], acc1, 0, 0, 0);
            }
            #pragma unroll
            for (int r = 0; r < 4; ++r) acc0[r] += acc1[r];
        }
        if (kg < 2) {
            #pragma unroll
            for (int r = 0; r < 4; ++r)
                sgate[q][hu][kg * 4 + r][col] = acc0[r];
        }
        __syncthreads();
        // ---- pointwise: 256 threads = (batch n 0..7, unit j 0..31) ----
        if (tid < 256) {
            int n = tid >> 5, j = tid & 31;
            int ng = G * 8 + n, jg = l * 32 + j;
            float iv = sgate[0][j >> 4][n][j & 15] + h2f(xi)  + sbias[0][j];
            float fv = sgate[1][j >> 4][n][j & 15] + h2f(xf)  + sbias[1][j];
            float gv = sgate[2][j >> 4][n][j & 15] + h2f(xgv) + sbias[2][j];
            float ov = sgate[3][j >> 4][n][j & 15] + h2f(xo)  + sbias[3][j];
            iv = 1.f / (1.f + __expf(-iv));
            fv = 1.f / (1.f + __expf(-fv));
            ov = 1.f / (1.f + __expf(-ov));
            float eg = __expf(2.f * gv);
            gv = 1.f - 2.f / (eg + 1.f);
            creg = fv * creg + iv * gv;
            float ec = __expf(2.f * creg);
            float hh = ov * (1.f - 2.f / (ec + 1.f));
            y[((size_t)ng << 19) + ((size_t)t << 10) + jg] = hh;
            unsigned short hb = f2bf(hh);
            if (s == TCH - 1) {
                hcan[((size_t)ng << 10) + jg] = hb;    // plain: next launch reads it
                cws[((size_t)ng << 10) + jg] = creg;
            } else {
                unsigned short* hp = (((t + 1) & 1) ? hxb1 : hxb0) + n * 1024 + jg;
                unsigned int hv = hb;
                asm volatile("global_store_short %0, %1, off sc0 sc1"
                             :: "v"(hp), "v"(hv) : "memory");
                // per-wave release: drain data stores, then one flag dword
                asm volatile("s_waitcnt vmcnt(0)" ::: "memory");
                if ((tid & 63) == 0) {
                    unsigned int tv = (unsigned int)(t + 1);
                    unsigned int* fw = flags + G * 128 + l * 4 + (tid >> 6);
                    asm volatile("global_store_dword %0, %1, off sc0 sc1"
                                 :: "v"(fw), "v"(tv) : "memory");
                }
            }
        }
    }
}

extern "C" void kernel_launch(void* const* d_in, const int* in_sizes, int n_in,
                              void* d_out, int out_size, void* d_ws, size_t ws_size,
                              hipStream_t stream) {
    const float* x   = (const float*)d_in[0];
    const float* wih = (const float*)d_in[1];
    const float* whh = (const float*)d_in[2];
    const float* bih = (const float*)d_in[3];
    const float* bhh = (const float*)d_in[4];
    float* y = (float*)d_out;

    char* ws = (char*)d_ws;
    unsigned short* Whh_bf = (unsigned short*)ws;                           // 8 MiB
    unsigned short* Wih_bf = (unsigned short*)(ws + ((size_t)8 << 20));     // 8 MiB
    unsigned short* xgc    = (unsigned short*)(ws + ((size_t)16 << 20));    // 64 MiB (f16)
    char* SB               = ws + ((size_t)80 << 20);
    float* biasc           = (float*)SB;                                    // 16 KiB
    char* zb               = SB + (16u << 10);
    unsigned short* hcan   = (unsigned short*)zb;                           // 128 KiB
    float* cws             = (float*)(zb + (128u << 10));                   // 256 KiB
    unsigned short* hx     = (unsigned short*)(zb + (384u << 10));          // 256 KiB
    unsigned int* flags    = (unsigned int*)(zb + (640u << 10));            // 4 KiB
    const int nz = (644 << 10) / 4;
    if (ws_size < ((size_t)81 << 20)) return;

    hipLaunchKernelGGL(cvt_mat, dim3(2048), dim3(256), 0, stream, whh, Whh_bf, G4 * HID / 8);
    hipLaunchKernelGGL(cvt_mat, dim3(2048), dim3(256), 0, stream, wih, Wih_bf, G4 * HID / 8);
    hipLaunchKernelGGL(init_kernel, dim3(648), dim3(256), 0, stream,
                       bih, bhh, biasc, (unsigned int*)zb, nz);

    for (int chk = 0; chk < NCH; ++chk) {
        int t0 = chk * TCH;
        hipLaunchKernelGGL(xg_gemm, dim3(2048), dim3(256), 0, stream, x, Wih_bf, xgc, t0);
        void* args[] = {(void*)&Whh_bf, (void*)&xgc, (void*)&biasc, (void*)&hcan,
                        (void*)&hx, (void*)&cws, (void*)&flags, (void*)&y, (void*)&t0};
        hipLaunchCooperativeKernel((const void*)lstm_persist, dim3(NWG), dim3(512),
                                   args, 0, stream);
    }
}

// Round 10
// 3219.328 us; speedup vs baseline: 1.1533x; 1.1533x over previous
//
#include <hip/hip_runtime.h>

#define HID 1024
#define G4 4096
#define TCH 128
#define NCH 4
#define NWG 256

typedef short short8 __attribute__((ext_vector_type(8)));
typedef float f32x4 __attribute__((ext_vector_type(4)));
typedef unsigned int u32x4 __attribute__((ext_vector_type(4)));

static __device__ __forceinline__ unsigned short f2bf(float f) {
    unsigned int u = __builtin_bit_cast(unsigned int, f);
    u += 0x7fffu + ((u >> 16) & 1u);
    return (unsigned short)(u >> 16);
}
static __device__ __forceinline__ unsigned short f2h(float v) {
    _Float16 h = (_Float16)v;
    return __builtin_bit_cast(unsigned short, h);
}
static __device__ __forceinline__ float h2f(unsigned short u) {
    return (float)__builtin_bit_cast(_Float16, u);
}

// fp32 -> bf16 bulk convert (n8 groups of 8)
__global__ void cvt_mat(const float* __restrict__ src, unsigned short* __restrict__ dst, int n8) {
    int idx = blockIdx.x * blockDim.x + threadIdx.x;
    if (idx >= n8) return;
    const float* s = src + (size_t)idx * 8;
    float4 a = *(const float4*)s;
    float4 b = *(const float4*)(s + 4);
    short8 v;
    v[0]=(short)f2bf(a.x); v[1]=(short)f2bf(a.y); v[2]=(short)f2bf(a.z); v[3]=(short)f2bf(a.w);
    v[4]=(short)f2bf(b.x); v[5]=(short)f2bf(b.y); v[6]=(short)f2bf(b.z); v[7]=(short)f2bf(b.w);
    *(short8*)(dst + (size_t)idx * 8) = v;
}

// zero state region (hcan, cws, hx), combine biases, bump per-replay nonce
__global__ void init_kernel(const float* __restrict__ bih, const float* __restrict__ bhh,
                            float* __restrict__ biasc, unsigned int* __restrict__ zbase,
                            int nz, unsigned int* __restrict__ nonce) {
    int i = blockIdx.x * blockDim.x + threadIdx.x;
    if (i < nz) zbase[i] = 0u;
    if (i < G4) biasc[i] = bih[i] + bhh[i];
    if (i == 0) nonce[0] = nonce[0] + 1u;
}

// xg[m][g] = sum_k x_chunk[m][k]*Wih[g][k], m = tl*64 + n; output f16 bits.
__global__ __launch_bounds__(256) void xg_gemm(
    const float* __restrict__ x,            // [64][512][1024] fp32
    const unsigned short* __restrict__ wb,  // Wih_bf [4096][1024]
    unsigned short* __restrict__ xg,        // [TCH*64][4096] f16 chunk
    int t0) {
    __shared__ unsigned short Al[128][72];
    __shared__ unsigned short Bl[128][72];
    const int tid = threadIdx.x, w = tid >> 6, lane = tid & 63;
    const int bm = blockIdx.x >> 5, bn = blockIdx.x & 31;
    const int wr = w >> 1, wc = w & 1;
    const int fr = lane & 15, kg = lane >> 4;
    f32x4 acc[4][4];
    #pragma unroll
    for (int i = 0; i < 4; ++i)
        #pragma unroll
        for (int j = 0; j < 4; ++j) acc[i][j] = (f32x4){0.f,0.f,0.f,0.f};

    for (int kt = 0; kt < 16; ++kt) {
        __syncthreads();
        #pragma unroll
        for (int c = 0; c < 4; ++c) {
            int idx = c * 256 + tid;
            int row = idx >> 3, co = (idx & 7) * 8;
            int m = bm * 128 + row;
            const float* sp = x + ((size_t)(m & 63) * 512 + (size_t)(t0 + (m >> 6))) * 1024
                                + kt * 64 + co;
            float4 a = *(const float4*)sp;
            float4 b = *(const float4*)(sp + 4);
            short8 v;
            v[0]=(short)f2bf(a.x); v[1]=(short)f2bf(a.y); v[2]=(short)f2bf(a.z); v[3]=(short)f2bf(a.w);
            v[4]=(short)f2bf(b.x); v[5]=(short)f2bf(b.y); v[6]=(short)f2bf(b.z); v[7]=(short)f2bf(b.w);
            *(short8*)&Al[row][co] = v;
            *(short8*)&Bl[row][co] = *(const short8*)(wb + (size_t)(bn * 128 + row) * 1024 + kt * 64 + co);
        }
        __syncthreads();
        #pragma unroll
        for (int kb = 0; kb < 2; ++kb) {
            short8 af[4], bf_[4];
            #pragma unroll
            for (int mi = 0; mi < 4; ++mi)
                af[mi] = *(const short8*)&Al[wr*64 + mi*16 + fr][kb*32 + kg*8];
            #pragma unroll
            for (int ni = 0; ni < 4; ++ni)
                bf_[ni] = *(const short8*)&Bl[wc*64 + ni*16 + fr][kb*32 + kg*8];
            #pragma unroll
            for (int mi = 0; mi < 4; ++mi)
                #pragma unroll
                for (int ni = 0; ni < 4; ++ni)
                    acc[mi][ni] = __builtin_amdgcn_mfma_f32_16x16x32_bf16(af[mi], bf_[ni], acc[mi][ni], 0, 0, 0);
        }
    }
    #pragma unroll
    for (int mi = 0; mi < 4; ++mi)
        #pragma unroll
        for (int ni = 0; ni < 4; ++ni)
            #pragma unroll
            for (int r = 0; r < 4; ++r) {
                int row = bm*128 + wr*64 + mi*16 + kg*4 + r;
                int col = bn*128 + wc*64 + ni*16 + fr;
                xg[(size_t)row * 4096 + col] = f2h(acc[mi][ni][r]);
            }
}

// Persistent LSTM chunk (128 steps). 256 WGs x 512 thr. R8 structure verbatim,
// ONE change: the 32 Whh fragments are 32 NAMED short8 locals, loaded once and
// pinned opaque via asm ("+v") so the compiler CANNOT rematerialize the loads
// inside the step loop (R8's VGPR_Count=108 proved bfr[32] was being re-streamed
// from L2 every step: 64 MB/step group-wide ~= 1.9 us/step).
// Transport: tag-in-data u32 {tag16|bf16} via sc0 sc1 (R8-proven); poll IS the
// data load; double buffer by parity; nonce-salted tags; bounded spins.
__global__ __launch_bounds__(512, 2) void lstm_persist(
    const unsigned short* __restrict__ whh,   // Whh_bf [4096][1024]
    const unsigned short* __restrict__ xg,    // [TCH*64][4096] f16 bits
    const float* __restrict__ biasc,          // [4096]
    unsigned short* __restrict__ hcan,        // [64][1024] bf16 chunk-boundary h
    unsigned int* __restrict__ hx,            // [2][8][8][1024] u32 tagged h
    float* __restrict__ cws,                  // [64][1024] chunk-boundary c
    const unsigned int* __restrict__ nonce,   // [1]
    float* __restrict__ y, int t0) {
    __shared__ unsigned short hA[16 * 1024];   // [16][1024] bf16, rows 8..15 zero, swizzled
    __shared__ float sgate[4][2][8][16];
    __shared__ float sbias[4][32];

    const int tid = threadIdx.x, w = tid >> 6, lane = tid & 63;
    const int G = (int)(blockIdx.x >> 5);
    const int l = (int)(blockIdx.x & 31);

    for (int i = tid; i < 8192; i += 512) hA[8192 + i] = 0;   // zero pad rows 8..15
    if (tid < 128) {
        int q = tid >> 5, j = tid & 31;
        sbias[q][j] = biasc[q * 1024 + l * 32 + j];
    }
    const int q = w & 3, hu = w >> 2;
    const int col = lane & 15, kg = lane >> 4;
    const unsigned int nonce6 = nonce[0] & 63u;

    // ---- Whh fragments: 32 named regs (128 VGPRs), loaded once, pinned ----
    const unsigned short* wp = whh + (size_t)(q * 1024 + l * 32 + hu * 16 + col) * 1024 + kg * 8;
#define LDW(i) short8 bw##i = *(const short8*)(wp + (i) * 32)
    LDW(0);  LDW(1);  LDW(2);  LDW(3);  LDW(4);  LDW(5);  LDW(6);  LDW(7);
    LDW(8);  LDW(9);  LDW(10); LDW(11); LDW(12); LDW(13); LDW(14); LDW(15);
    LDW(16); LDW(17); LDW(18); LDW(19); LDW(20); LDW(21); LDW(22); LDW(23);
    LDW(24); LDW(25); LDW(26); LDW(27); LDW(28); LDW(29); LDW(30); LDW(31);
#undef LDW
#define PIN8(a,b,c,d,e,f,g,h) asm volatile("" : "+v"(a),"+v"(b),"+v"(c),"+v"(d),"+v"(e),"+v"(f),"+v"(g),"+v"(h))
    PIN8(bw0,  bw1,  bw2,  bw3,  bw4,  bw5,  bw6,  bw7);
    PIN8(bw8,  bw9,  bw10, bw11, bw12, bw13, bw14, bw15);
    PIN8(bw16, bw17, bw18, bw19, bw20, bw21, bw22, bw23);
    PIN8(bw24, bw25, bw26, bw27, bw28, bw29, bw30, bw31);
#undef PIN8

    float creg = 0.f;
    if (tid < 256) {
        int n = tid >> 5, j = tid & 31;
        creg = cws[((size_t)(G * 8 + n) << 10) + l * 32 + j];
    }
    __syncthreads();

    const int sn = tid >> 6;   // staging batch row 0..7 (one per wave)
    unsigned int* hxb0 = hx + (size_t)G * 8192;
    unsigned int* hxb1 = hx + (size_t)(8 + G) * 8192;

    for (int s = 0; s < TCH; ++s) {
        const int t = t0 + s;
        // ---- xg prefetch (plain loads; complete under the poll) ----
        unsigned short xi = 0, xf = 0, xgv = 0, xo = 0;
        if (tid < 256) {
            int n = tid >> 5, j = tid & 31;
            const unsigned short* xp = xg + ((size_t)(s * 64 + G * 8 + n) << 12) + l * 32 + j;
            xi = xp[0]; xf = xp[1024]; xgv = xp[2048]; xo = xp[3072];
        }
        // ---- acquire h(t): poll-with-data (tag-in-data, one RT) ----
        short8 v0, v1;
        if (s == 0) {
            const unsigned short* hp = hcan + ((size_t)(G * 8 + sn) << 10) + lane * 16;
            v0 = *(const short8*)hp;
            v1 = *(const short8*)(hp + 8);
        } else {
            const unsigned int* pp = ((t & 1) ? hxb1 : hxb0) + sn * 1024 + lane * 16;
            const unsigned int ttag = (nonce6 << 10) | ((unsigned)t & 1023u);
            u32x4 w0, w1, w2, w3;
            int guard = 0;
            while (true) {
                asm volatile("global_load_dwordx4 %0, %1, off sc0 sc1" : "=v"(w0) : "v"(pp)      : "memory");
                asm volatile("global_load_dwordx4 %0, %1, off sc0 sc1" : "=v"(w1) : "v"(pp + 4)  : "memory");
                asm volatile("global_load_dwordx4 %0, %1, off sc0 sc1" : "=v"(w2) : "v"(pp + 8)  : "memory");
                asm volatile("global_load_dwordx4 %0, %1, off sc0 sc1" : "=v"(w3) : "v"(pp + 12) : "memory");
                asm volatile("s_waitcnt vmcnt(0)"
                             : "+v"(w0), "+v"(w1), "+v"(w2), "+v"(w3) :: "memory");
                int ok = 1;
                #pragma unroll
                for (int e = 0; e < 4; ++e) {
                    ok &= ((w0[e] >> 16) == ttag);
                    ok &= ((w1[e] >> 16) == ttag);
                    ok &= ((w2[e] >> 16) == ttag);
                    ok &= ((w3[e] >> 16) == ttag);
                }
                if (__all(ok) || ++guard > 100000) break;
            }
            #pragma unroll
            for (int e = 0; e < 4; ++e) {
                v0[e]     = (short)(w0[e] & 0xffffu);
                v0[4 + e] = (short)(w1[e] & 0xffffu);
                v1[e]     = (short)(w2[e] & 0xffffu);
                v1[4 + e] = (short)(w3[e] & 0xffffu);
            }
        }
        {   // stage into hA (XOR-swizzled 16B groups)
            int cg0 = lane * 2;
            char* base = (char*)hA + sn * 2048;
            *(short8*)(base + (((unsigned)(cg0       ^ (sn & 7))) << 4)) = v0;
            *(short8*)(base + (((unsigned)((cg0 + 1) ^ (sn & 7))) << 4)) = v1;
        }
        __syncthreads();
        // ---- recurrent MFMA: M=16 (8 real rows) x N=16 units x K=1024 ----
        f32x4 acc0 = {0.f,0.f,0.f,0.f}, acc1 = {0.f,0.f,0.f,0.f};
        {
            const int row = lane & 15;
            const unsigned rsw = (unsigned)(row & 7);
            const char* base = (const char*)hA + row * 2048;
#define KSTEP(k0,k1) do { \
            int cgA = (k0) * 4 + kg; \
            short8 a0 = *(const short8*)(base + (((unsigned)(cgA       ^ rsw)) << 4)); \
            short8 a1 = *(const short8*)(base + (((unsigned)((cgA + 4) ^ rsw)) << 4)); \
            acc0 = __builtin_amdgcn_mfma_f32_16x16x32_bf16(a0, bw##k0, acc0, 0, 0, 0); \
            acc1 = __builtin_amdgcn_mfma_f32_16x16x32_bf16(a1, bw##k1, acc1, 0, 0, 0); \
        } while (0)
            KSTEP(0,1);   KSTEP(2,3);   KSTEP(4,5);   KSTEP(6,7);
            KSTEP(8,9);   KSTEP(10,11); KSTEP(12,13); KSTEP(14,15);
            KSTEP(16,17); KSTEP(18,19); KSTEP(20,21); KSTEP(22,23);
            KSTEP(24,25); KSTEP(26,27); KSTEP(28,29); KSTEP(30,31);
#undef KSTEP
            #pragma unroll
            for (int r = 0; r < 4; ++r) acc0[r] += acc1[r];
        }
        if (kg < 2) {
            #pragma unroll
            for (int r = 0; r < 4; ++r)
                sgate[q][hu][kg * 4 + r][col] = acc0[r];
        }
        __syncthreads();
        // ---- pointwise: 256 threads = (batch n 0..7, unit j 0..31) ----
        if (tid < 256) {
            int n = tid >> 5, j = tid & 31;
            int ng = G * 8 + n, jg = l * 32 + j;
            float iv = sgate[0][j >> 4][n][j & 15] + h2f(xi)  + sbias[0][j];
            float fv = sgate[1][j >> 4][n][j & 15] + h2f(xf)  + sbias[1][j];
            float gv = sgate[2][j >> 4][n][j & 15] + h2f(xgv) + sbias[2][j];
            float ov = sgate[3][j >> 4][n][j & 15] + h2f(xo)  + sbias[3][j];
            iv = 1.f / (1.f + __expf(-iv));
            fv = 1.f / (1.f + __expf(-fv));
            ov = 1.f / (1.f + __expf(-ov));
            float eg = __expf(2.f * gv);
            gv = 1.f - 2.f / (eg + 1.f);
            creg = fv * creg + iv * gv;
            float ec = __expf(2.f * creg);
            float hh = ov * (1.f - 2.f / (ec + 1.f));
            y[((size_t)ng << 19) + ((size_t)t << 10) + jg] = hh;
            unsigned short hb = f2bf(hh);
            if (s == TCH - 1) {
                hcan[((size_t)ng << 10) + jg] = hb;    // plain: next launch reads it
                cws[((size_t)ng << 10) + jg] = creg;
            } else {
                unsigned int wv = (((nonce6 << 10) | ((unsigned)(t + 1) & 1023u)) << 16)
                                  | (unsigned int)hb;
                unsigned int* hp = (((t + 1) & 1) ? hxb1 : hxb0) + n * 1024 + jg;
                asm volatile("global_store_dword %0, %1, off sc0 sc1"
                             :: "v"(hp), "v"(wv) : "memory");
            }
        }
    }
}

extern "C" void kernel_launch(void* const* d_in, const int* in_sizes, int n_in,
                              void* d_out, int out_size, void* d_ws, size_t ws_size,
                              hipStream_t stream) {
    const float* x   = (const float*)d_in[0];
    const float* wih = (const float*)d_in[1];
    const float* whh = (const float*)d_in[2];
    const float* bih = (const float*)d_in[3];
    const float* bhh = (const float*)d_in[4];
    float* y = (float*)d_out;

    char* ws = (char*)d_ws;
    unsigned short* Whh_bf = (unsigned short*)ws;                           // 8 MiB
    unsigned short* Wih_bf = (unsigned short*)(ws + ((size_t)8 << 20));     // 8 MiB
    unsigned short* xgc    = (unsigned short*)(ws + ((size_t)16 << 20));    // 64 MiB (f16)
    char* SB               = ws + ((size_t)80 << 20);
    float* biasc           = (float*)SB;                                    // 16 KiB
    char* zb               = SB + (16u << 10);
    unsigned short* hcan   = (unsigned short*)zb;                           // 128 KiB
    float* cws             = (float*)(zb + (128u << 10));                   // 256 KiB
    unsigned int* hx       = (unsigned int*)(zb + (384u << 10));            // 512 KiB
    unsigned int* nonce    = (unsigned int*)(zb + (896u << 10));            // 4 B (NOT zeroed)
    const int nz = (896 << 10) / 4;
    if (ws_size < ((size_t)81 << 20)) return;

    hipLaunchKernelGGL(cvt_mat, dim3(2048), dim3(256), 0, stream, whh, Whh_bf, G4 * HID / 8);
    hipLaunchKernelGGL(cvt_mat, dim3(2048), dim3(256), 0, stream, wih, Wih_bf, G4 * HID / 8);
    hipLaunchKernelGGL(init_kernel, dim3(896), dim3(256), 0, stream,
                       bih, bhh, biasc, (unsigned int*)zb, nz, nonce);

    for (int chk = 0; chk < NCH; ++chk) {
        int t0 = chk * TCH;
        hipLaunchKernelGGL(xg_gemm, dim3(2048), dim3(256), 0, stream, x, Wih_bf, xgc, t0);
        void* args[] = {(void*)&Whh_bf, (void*)&xgc, (void*)&biasc, (void*)&hcan,
                        (void*)&hx, (void*)&cws, (void*)&nonce, (void*)&y, (void*)&t0};
        hipLaunchCooperativeKernel((const void*)lstm_persist, dim3(NWG), dim3(512),
                                   args, 0, stream);
    }
}